// Round 10
// baseline (132.022 us; speedup 1.0000x reference)
//
#include <hip/hip_runtime.h>
#include <hip/hip_fp16.h>
#include <math.h>

#define EMB_DIM 500
#define TWO_D 1000
#define D4 125                 // float4 groups per half-row (500/4)
#define ROW_F4 250             // float4 per entity row (1000/4)
#define NUM_ENTITIES 14541
#define B_SIZE 16
#define GAMMA_F 12.0f
// PI / ((GAMMA + 2) / EMB_DIM) = pi / 0.028
#define PHASE_SCALE 112.19973762820692f
#define ROT_HALFS (B_SIZE * D4 * 8)   // 16000 halfs = 32000 B
#define NP (B_SIZE * NUM_ENTITIES)    // 232656 partial elems per d-half

// ---------------------------------------------------------------------------
// Kernel 1: precompute rotated head embeddings as fp16, interleaved layout
// rot[b][d4][0..3] = re(4*d4 .. 4*d4+3), rot[b][d4][4..7] = im(...)
// ---------------------------------------------------------------------------
__global__ __launch_bounds__(256) void rot_precompute(
    const int* __restrict__ all_h, const int* __restrict__ all_r,
    const float* __restrict__ eemb, const float* __restrict__ remb,
    __half* __restrict__ rot)
{
    int i = blockIdx.x * 256 + threadIdx.x;
    if (i >= B_SIZE * EMB_DIM) return;
    int b = i / EMB_DIM;
    int d = i - b * EMB_DIM;
    int h = all_h[b];
    int r = all_r[b];
    float re_h = eemb[h * TWO_D + d];
    float im_h = eemb[h * TWO_D + EMB_DIM + d];
    float ph = remb[r * EMB_DIM + d] * PHASE_SCALE;
    float s, c;
    sincosf(ph, &s, &c);
    int base = ((b * D4 + (d >> 2)) << 3) + (d & 3);
    rot[base]     = __float2half(re_h * c - im_h * s);  // re_rot
    rot[base + 4] = __float2half(re_h * s + im_h * c);  // im_rot
}

// ---------------------------------------------------------------------------
// Kernel 2 (pass 1): NO LDS. Each block = (entity-tile of 8) x (one d-half).
// Wave owns 2 entities x its d4 slice (d4 = dh*64 + lane). The rot slice for
// all 16 b lives in 64 VGPRs (fp16 float4 each), loaded once from the global
// rot table (32 KB, L2-resident). Inner loop is pure VALU + 4 global loads.
// Writes partial sums to ws; kernel 3 combines the two d-halves.
// ---------------------------------------------------------------------------
__global__ __launch_bounds__(256) void rotate_partial(
    const float* __restrict__ eemb,
    const __half* __restrict__ rot,
    float* __restrict__ partial)         // [2][B_SIZE][NUM_ENTITIES]
{
    const int tid  = threadIdx.x;
    const int lane = tid & 63;
    const int wave = tid >> 6;
    const int etile = blockIdx.x >> 1;
    const int dh    = blockIdx.x & 1;
    const int e0 = etile * 8 + wave * 2;

    const int d4  = dh * 64 + lane;
    const bool valid = (d4 < D4);
    const int d4c = valid ? d4 : (D4 - 1);

    const float4* rot4 = (const float4*)rot;
    const float4* ee4  = (const float4*)eemb;

    // rot slice for this lane's d4: 16 x float4 (fp16 pairs) = 64 VGPRs
    float4 rv[16];
#pragma unroll
    for (int b = 0; b < 16; ++b) rv[b] = rot4[b * D4 + d4c];

    int e[2];
#pragma unroll
    for (int k = 0; k < 2; ++k) {
        int ek = e0 + k;
        e[k] = (ek < NUM_ENTITIES) ? ek : (NUM_ENTITIES - 1);
    }

    float4 tre[2], tim[2];
#pragma unroll
    for (int k = 0; k < 2; ++k) {
        int rb = e[k] * ROW_F4;
        tre[k] = ee4[rb + d4c];
        tim[k] = ee4[rb + D4 + d4c];
    }

    float v[32];                         // acc[k][b]: idx = k*16+b
#pragma unroll
    for (int i = 0; i < 32; ++i) v[i] = 0.0f;

    if (valid) {
#pragma unroll
        for (int b = 0; b < 16; ++b) {
            __half2 p0 = __builtin_bit_cast(__half2, rv[b].x);
            __half2 p1 = __builtin_bit_cast(__half2, rv[b].y);
            __half2 p2 = __builtin_bit_cast(__half2, rv[b].z);
            __half2 p3 = __builtin_bit_cast(__half2, rv[b].w);
            float rre0 = __low2float(p0), rre1 = __high2float(p0);
            float rre2 = __low2float(p1), rre3 = __high2float(p1);
            float rim0 = __low2float(p2), rim1 = __high2float(p2);
            float rim2 = __low2float(p3), rim3 = __high2float(p3);
#pragma unroll
            for (int k = 0; k < 2; ++k) {
                float dre, dim;
                dre = rre0 - tre[k].x; dim = rim0 - tim[k].x;
                v[k * 16 + b] += __builtin_amdgcn_sqrtf(dre * dre + dim * dim);
                dre = rre1 - tre[k].y; dim = rim1 - tim[k].y;
                v[k * 16 + b] += __builtin_amdgcn_sqrtf(dre * dre + dim * dim);
                dre = rre2 - tre[k].z; dim = rim2 - tim[k].z;
                v[k * 16 + b] += __builtin_amdgcn_sqrtf(dre * dre + dim * dim);
                dre = rre3 - tre[k].w; dim = rim3 - tim[k].w;
                v[k * 16 + b] += __builtin_amdgcn_sqrtf(dre * dre + dim * dim);
            }
        }
    }

    // Fold lane^32, then 5-stage halving butterfly over low 5 lane bits:
    // lane L in [0,32) ends with the full 64-lane sum of v[L].
#pragma unroll
    for (int i = 0; i < 32; ++i) v[i] += __shfl_xor(v[i], 32, 64);
#pragma unroll
    for (int m = 16; m >= 1; m >>= 1) {
        const bool hi = (lane & m) != 0;
#pragma unroll
        for (int i = 0; i < m; ++i) {
            float give = hi ? v[i] : v[m + i];
            float keep = hi ? v[m + i] : v[i];
            v[i] = keep + __shfl_xor(give, m, 64);
        }
    }

    if (lane < 32) {
        const int kk = lane >> 4;        // 0..1
        const int bb = lane & 15;        // 0..15
        const int ee = e0 + kk;
        if (ee < NUM_ENTITIES)
            partial[dh * NP + bb * NUM_ENTITIES + ee] = v[0];
    }
}

// ---------------------------------------------------------------------------
// Kernel 3 (pass 2): out = GAMMA - (p0 + p1), vectorized float4.
// ---------------------------------------------------------------------------
__global__ __launch_bounds__(256) void combine(
    const float* __restrict__ partial, float* __restrict__ out)
{
    int i = blockIdx.x * 256 + threadIdx.x;
    const int n4 = NP / 4;               // 58164
    if (i >= n4) return;
    const float4* p0 = (const float4*)partial;
    const float4* p1 = (const float4*)(partial + NP);
    float4 a = p0[i], b = p1[i];
    float4 r;
    r.x = GAMMA_F - (a.x + b.x);
    r.y = GAMMA_F - (a.y + b.y);
    r.z = GAMMA_F - (a.z + b.z);
    r.w = GAMMA_F - (a.w + b.w);
    ((float4*)out)[i] = r;
}

// ---------------------------------------------------------------------------
// Fallback (ws-starved): R9's LDS kernel with inline rot compute.
// ---------------------------------------------------------------------------
__global__ __launch_bounds__(256) void rotate_score_fb(
    const float* __restrict__ eemb,
    const int* __restrict__ all_h, const int* __restrict__ all_r,
    const float* __restrict__ remb,
    float* __restrict__ out)
{
    __shared__ __half lrot[ROT_HALFS];
    const int tid = threadIdx.x;
    for (int i = tid; i < B_SIZE * EMB_DIM; i += 256) {
        int b = i / EMB_DIM;
        int d = i - b * EMB_DIM;
        int h = all_h[b];
        int r = all_r[b];
        float re_h = eemb[h * TWO_D + d];
        float im_h = eemb[h * TWO_D + EMB_DIM + d];
        float ph = remb[r * EMB_DIM + d] * PHASE_SCALE;
        float s, c;
        sincosf(ph, &s, &c);
        int base = ((b * D4 + (d >> 2)) << 3) + (d & 3);
        lrot[base]     = __float2half(re_h * c - im_h * s);
        lrot[base + 4] = __float2half(re_h * s + im_h * c);
    }
    __syncthreads();

    const int lane = tid & 63;
    const int wave = tid >> 6;
    const int e0 = blockIdx.x * 16 + wave * 4;
    int e[4];
#pragma unroll
    for (int k = 0; k < 4; ++k) {
        int ek = e0 + k;
        e[k] = (ek < NUM_ENTITIES) ? ek : (NUM_ENTITIES - 1);
    }
    float v[64];
#pragma unroll
    for (int i = 0; i < 64; ++i) v[i] = 0.0f;
    const float4* lrot4 = (const float4*)lrot;
    const float4* ee4 = (const float4*)eemb;
#pragma unroll
    for (int it = 0; it < 2; ++it) {
        const int d4 = it * 64 + lane;
        if (d4 < D4) {
            float4 tre[4], tim[4];
#pragma unroll
            for (int k = 0; k < 4; ++k) {
                int rb = e[k] * ROW_F4;
                tre[k] = ee4[rb + d4];
                tim[k] = ee4[rb + D4 + d4];
            }
#pragma unroll
            for (int b = 0; b < 16; ++b) {
                float4 rvb = lrot4[b * D4 + d4];
                __half2 p0 = __builtin_bit_cast(__half2, rvb.x);
                __half2 p1 = __builtin_bit_cast(__half2, rvb.y);
                __half2 p2 = __builtin_bit_cast(__half2, rvb.z);
                __half2 p3 = __builtin_bit_cast(__half2, rvb.w);
                float rre0 = __low2float(p0), rre1 = __high2float(p0);
                float rre2 = __low2float(p1), rre3 = __high2float(p1);
                float rim0 = __low2float(p2), rim1 = __high2float(p2);
                float rim2 = __low2float(p3), rim3 = __high2float(p3);
#pragma unroll
                for (int k = 0; k < 4; ++k) {
                    float dre, dim;
                    dre = rre0 - tre[k].x; dim = rim0 - tim[k].x;
                    v[k * 16 + b] += __builtin_amdgcn_sqrtf(dre * dre + dim * dim);
                    dre = rre1 - tre[k].y; dim = rim1 - tim[k].y;
                    v[k * 16 + b] += __builtin_amdgcn_sqrtf(dre * dre + dim * dim);
                    dre = rre2 - tre[k].z; dim = rim2 - tim[k].z;
                    v[k * 16 + b] += __builtin_amdgcn_sqrtf(dre * dre + dim * dim);
                    dre = rre3 - tre[k].w; dim = rim3 - tim[k].w;
                    v[k * 16 + b] += __builtin_amdgcn_sqrtf(dre * dre + dim * dim);
                }
            }
        }
    }
#pragma unroll
    for (int m = 32; m >= 1; m >>= 1) {
        const bool hi = (lane & m) != 0;
#pragma unroll
        for (int i = 0; i < m; ++i) {
            float give = hi ? v[i] : v[m + i];
            float keep = hi ? v[m + i] : v[i];
            v[i] = keep + __shfl_xor(give, m, 64);
        }
    }
    const int kk = lane >> 4;
    const int bb = lane & 15;
    const int ee = e0 + kk;
    if (ee < NUM_ENTITIES) out[bb * NUM_ENTITIES + ee] = GAMMA_F - v[0];
}

extern "C" void kernel_launch(void* const* d_in, const int* in_sizes, int n_in,
                              void* d_out, int out_size, void* d_ws, size_t ws_size,
                              hipStream_t stream) {
    const int*   all_h = (const int*)d_in[0];
    const int*   all_r = (const int*)d_in[1];
    const float* eemb  = (const float*)d_in[2];
    const float* remb  = (const float*)d_in[3];
    float* out = (float*)d_out;

    const size_t part_bytes = (size_t)2 * NP * sizeof(float);       // 1.86 MB
    const size_t rot_bytes  = (size_t)ROT_HALFS * sizeof(__half);   // 32 KB
    if (ws_size >= part_bytes + rot_bytes) {
        float*  part = (float*)d_ws;
        __half* rot  = (__half*)((char*)d_ws + part_bytes);
        rot_precompute<<<(B_SIZE * EMB_DIM + 255) / 256, 256, 0, stream>>>(
            all_h, all_r, eemb, remb, rot);
        int etiles = (NUM_ENTITIES + 7) / 8;                        // 1818
        rotate_partial<<<etiles * 2, 256, 0, stream>>>(eemb, rot, part);
        combine<<<(NP / 4 + 255) / 256, 256, 0, stream>>>(part, out);
    } else {
        int nblocks = (NUM_ENTITIES + 15) / 16;                     // 909
        rotate_score_fb<<<nblocks, 256, 0, stream>>>(eemb, all_h, all_r, remb, out);
    }
}

// Round 11
// 70.113 us; speedup vs baseline: 1.8830x; 1.8830x over previous
//
#include <hip/hip_runtime.h>
#include <hip/hip_fp16.h>
#include <math.h>

#define EMB_DIM 500
#define TWO_D 1000
#define D4 125                 // float4 groups per half-row (500/4)
#define ROW_F4 250             // float4 per entity row (1000/4)
#define NUM_ENTITIES 14541
#define B_SIZE 16
#define GAMMA_F 12.0f
// PI / ((GAMMA + 2) / EMB_DIM) = pi / 0.028
#define PHASE_SCALE 112.19973762820692f
#define ROT_HALFS (B_SIZE * D4 * 8)   // 16000 halfs = 32000 B

// ---------------------------------------------------------------------------
// Kernel 1: precompute rotated head embeddings as fp16, interleaved layout
// rot[b][d4][0..3] = re(4*d4 .. 4*d4+3), rot[b][d4][4..7] = im(...)
// ---------------------------------------------------------------------------
__global__ __launch_bounds__(256) void rot_precompute(
    const int* __restrict__ all_h, const int* __restrict__ all_r,
    const float* __restrict__ eemb, const float* __restrict__ remb,
    __half* __restrict__ rot)
{
    int i = blockIdx.x * 256 + threadIdx.x;
    if (i >= B_SIZE * EMB_DIM) return;
    int b = i / EMB_DIM;
    int d = i - b * EMB_DIM;
    int h = all_h[b];
    int r = all_r[b];
    float re_h = eemb[h * TWO_D + d];
    float im_h = eemb[h * TWO_D + EMB_DIM + d];
    float ph = remb[r * EMB_DIM + d] * PHASE_SCALE;
    float s, c;
    sincosf(ph, &s, &c);
    int base = ((b * D4 + (d >> 2)) << 3) + (d & 3);
    rot[base]     = __float2half(re_h * c - im_h * s);  // re_rot
    rot[base + 4] = __float2half(re_h * s + im_h * c);  // im_rot
}

// ---------------------------------------------------------------------------
// Kernel 2: block = 16 entities, 4 waves. Each wave handles 4 entities, but
// SPLIT ACROSS HALF-WAVES: lanes 0-31 own ents e0..e0+1, lanes 32-63 own
// e0+2..e0+3; each lane covers d4 = (lane&31)+32*it, it=0..3.
// -> 32 accumulators/lane (vs R9's 64): ~80-96 VGPR, 5 waves/SIMD (vs 2).
// Same 3636 waves / per-wave work as R9 (39us); R5/R10 showed more waves
// with less work each = worse (97/132us). LDS rot reads broadcast across
// halves (same addr); butterfly m=16..1 stays within each 32-lane half.
// ---------------------------------------------------------------------------
__global__ __launch_bounds__(256) void rotate_score(
    const float* __restrict__ eemb,
    const __half* __restrict__ rot,      // nullptr -> compute in-kernel
    const int* __restrict__ all_h, const int* __restrict__ all_r,
    const float* __restrict__ remb,
    float* __restrict__ out)
{
    __shared__ __half lrot[ROT_HALFS];   // 32000 bytes -> 5 blocks/CU

    const int tid = threadIdx.x;

    if (rot != nullptr) {
        const float4* src = (const float4*)rot;
        float4* dst = (float4*)lrot;
        for (int i = tid; i < ROT_HALFS / 8; i += 256) dst[i] = src[i];
    } else {
        for (int i = tid; i < B_SIZE * EMB_DIM; i += 256) {
            int b = i / EMB_DIM;
            int d = i - b * EMB_DIM;
            int h = all_h[b];
            int r = all_r[b];
            float re_h = eemb[h * TWO_D + d];
            float im_h = eemb[h * TWO_D + EMB_DIM + d];
            float ph = remb[r * EMB_DIM + d] * PHASE_SCALE;
            float s, c;
            sincosf(ph, &s, &c);
            int base = ((b * D4 + (d >> 2)) << 3) + (d & 3);
            lrot[base]     = __float2half(re_h * c - im_h * s);
            lrot[base + 4] = __float2half(re_h * s + im_h * c);
        }
    }
    __syncthreads();

    const int lane = tid & 63;
    const int wave = tid >> 6;
    const int half = lane >> 5;          // 0..1: which entity pair
    const int L    = lane & 31;          // lane within half
    const int e0 = blockIdx.x * 16 + wave * 4 + half * 2;

    int e[2];
#pragma unroll
    for (int k = 0; k < 2; ++k) {
        int ek = e0 + k;
        e[k] = (ek < NUM_ENTITIES) ? ek : (NUM_ENTITIES - 1);
    }

    float v[32];                         // acc[k][b]: idx = k*16+b
#pragma unroll
    for (int i = 0; i < 32; ++i) v[i] = 0.0f;

    const float4* lrot4 = (const float4*)lrot;
    const float4* ee4 = (const float4*)eemb;

#pragma unroll
    for (int it = 0; it < 4; ++it) {
        const int d4 = it * 32 + L;
        if (d4 < D4) {
            float4 tre[2], tim[2];
#pragma unroll
            for (int k = 0; k < 2; ++k) {
                int rb = e[k] * ROW_F4;
                tre[k] = ee4[rb + d4];
                tim[k] = ee4[rb + D4 + d4];
            }
#pragma unroll
            for (int b = 0; b < 16; ++b) {
                float4 rv = lrot4[b * D4 + d4];   // same addr in both halves
                __half2 p0 = __builtin_bit_cast(__half2, rv.x);
                __half2 p1 = __builtin_bit_cast(__half2, rv.y);
                __half2 p2 = __builtin_bit_cast(__half2, rv.z);
                __half2 p3 = __builtin_bit_cast(__half2, rv.w);
                float rre0 = __low2float(p0), rre1 = __high2float(p0);
                float rre2 = __low2float(p1), rre3 = __high2float(p1);
                float rim0 = __low2float(p2), rim1 = __high2float(p2);
                float rim2 = __low2float(p3), rim3 = __high2float(p3);
#pragma unroll
                for (int k = 0; k < 2; ++k) {
                    float dre, dim;
                    dre = rre0 - tre[k].x; dim = rim0 - tim[k].x;
                    v[k * 16 + b] += __builtin_amdgcn_sqrtf(dre * dre + dim * dim);
                    dre = rre1 - tre[k].y; dim = rim1 - tim[k].y;
                    v[k * 16 + b] += __builtin_amdgcn_sqrtf(dre * dre + dim * dim);
                    dre = rre2 - tre[k].z; dim = rim2 - tim[k].z;
                    v[k * 16 + b] += __builtin_amdgcn_sqrtf(dre * dre + dim * dim);
                    dre = rre3 - tre[k].w; dim = rim3 - tim[k].w;
                    v[k * 16 + b] += __builtin_amdgcn_sqrtf(dre * dre + dim * dim);
                }
            }
        }
    }

    // Halving butterfly within each 32-lane half (xor of bits 0-4 never
    // crosses the half boundary): afterwards lane with (lane&31)==L holds
    // the 32-lane sum of acc[L] for its half's entity pair.
#pragma unroll
    for (int m = 16; m >= 1; m >>= 1) {
        const bool hi = (L & m) != 0;
#pragma unroll
        for (int i = 0; i < m; ++i) {
            float give = hi ? v[i] : v[m + i];
            float keep = hi ? v[m + i] : v[i];
            v[i] = keep + __shfl_xor(give, m, 64);
        }
    }

    const int kk = L >> 4;               // 0..1 within the half's pair
    const int bb = L & 15;               // 0..15
    const int ee = e0 + kk;
    if (ee < NUM_ENTITIES) out[bb * NUM_ENTITIES + ee] = GAMMA_F - v[0];
}

extern "C" void kernel_launch(void* const* d_in, const int* in_sizes, int n_in,
                              void* d_out, int out_size, void* d_ws, size_t ws_size,
                              hipStream_t stream) {
    const int*   all_h = (const int*)d_in[0];
    const int*   all_r = (const int*)d_in[1];
    const float* eemb  = (const float*)d_in[2];
    const float* remb  = (const float*)d_in[3];
    float* out = (float*)d_out;

    __half* rot = nullptr;
    const size_t rot_bytes = (size_t)ROT_HALFS * sizeof(__half);
    if (ws_size >= rot_bytes) {
        rot = (__half*)d_ws;
        rot_precompute<<<(B_SIZE * EMB_DIM + 255) / 256, 256, 0, stream>>>(
            all_h, all_r, eemb, remb, rot);
    }

    int nblocks = (NUM_ENTITIES + 15) / 16;  // 909
    rotate_score<<<nblocks, 256, 0, stream>>>(eemb, rot, all_h, all_r, remb, out);
}